// Round 13
// baseline (616.612 us; speedup 1.0000x reference)
//
#include <hip/hip_runtime.h>
#include <cstdint>
#include <cstddef>

// ---------------------------------------------------------------------------
// BsPINN forward, single-fp16 MFMA, pipelined producer/consumer (round 13).
// R12 fault: producer issued loads AFTER each barrier and __syncthreads'
// vmcnt(0) drained them -> full L2 latency per iter on the critical path.
// R13: producer runs one iteration ahead (loads for t+2 in flight across a
// RAW s_barrier; only lgkmcnt drained manually), triple-buffered LDS.
// Consumers (waves 0-3) = R12's proven 128x128 fragment path, plain
// __syncthreads (no global loads in-loop -> their vmcnt drain is free).
//   h0 = tanh(norm(X) @ W0 + b0)        K=2   fp32 vector
//   h1 = tanh(h0 @ W1 + b1)             K=1024 MFMA f16
//   h2 = tanh(h1 @ (W2*m2) + b2)        2 x 512 block-diag (K=512)
//   out = tanh(h2 @ (W3*m3) + b3) @ W_last + b_last   (fused, K=256)
// fp16 error model validated R10/R11 (absmax 2.44e-4 << 9.2e-4).
// ---------------------------------------------------------------------------

typedef _Float16  f16x8   __attribute__((ext_vector_type(8)));
typedef float     floatx4 __attribute__((ext_vector_type(4)));
typedef float     floatx8 __attribute__((ext_vector_type(8)));

__device__ __forceinline__ float tanh_fast(float x) {
    float e = __expf(2.0f * x);
    return 1.0f - 2.0f / (e + 1.0f);
}

// ---------------------------------------------------------------------------
// Weight transpose + f16 convert, all three weights in one launch (z picks).
// ---------------------------------------------------------------------------
__global__ __launch_bounds__(256)
void transposeH3(const float* __restrict__ W1, const float* __restrict__ W2,
                 const float* __restrict__ W3, _Float16* __restrict__ Wt1,
                 _Float16* __restrict__ Wt2, _Float16* __restrict__ Wt3) {
    const float* W = blockIdx.z == 0 ? W1 : (blockIdx.z == 1 ? W2 : W3);
    _Float16* Wt   = blockIdx.z == 0 ? Wt1 : (blockIdx.z == 1 ? Wt2 : Wt3);
    __shared__ float tile[32][33];
    const int tx = threadIdx.x & 31;
    const int ty = threadIdx.x >> 5;     // 0..7
    #pragma unroll
    for (int j = 0; j < 4; ++j) {
        int r = ty + j * 8;
        tile[r][tx] = W[(size_t)(blockIdx.y * 32 + r) * 1024 + blockIdx.x * 32 + tx];
    }
    __syncthreads();
    #pragma unroll
    for (int j = 0; j < 4; ++j) {
        int r = ty + j * 8;
        Wt[(size_t)(blockIdx.x * 32 + r) * 1024 + blockIdx.y * 32 + tx] =
            (_Float16)tile[tx][r];
    }
}

// ---------------------------------------------------------------------------
// out[row] := b_last — re-initialized every call before layer3 atomics.
// ---------------------------------------------------------------------------
__global__ __launch_bounds__(256)
void init_out(float* __restrict__ out, const float* __restrict__ bl) {
    out[blockIdx.x * 256 + threadIdx.x] = bl[0];
}

// ---------------------------------------------------------------------------
// Layer 0 (fp32 in): h0 = tanh(xa*W0[0][:] + xb*W0[1][:] + b0) -> f16.
// ---------------------------------------------------------------------------
__global__ __launch_bounds__(256)
void layer0_kernel(const float* __restrict__ X, const float* __restrict__ W0,
                   const float* __restrict__ b0, _Float16* __restrict__ H) {
    const int idx = blockIdx.x * 256 + threadIdx.x;
    const int row = idx >> 7;
    const int j0  = (idx & 127) << 3;
    const float x0 = X[row * 2 + 0];
    const float x1 = X[row * 2 + 1];
    const float xa = x0 * 0.31830988618379067f - 1.0f;   // x0/pi - 1
    const float xb = 2.0f * x1 - 1.0f;
    floatx8 wa = *(const floatx8*)(W0 + j0);
    floatx8 wb = *(const floatx8*)(W0 + 1024 + j0);
    floatx8 bb = *(const floatx8*)(b0 + j0);
    f16x8 o;
    #pragma unroll
    for (int j = 0; j < 8; ++j) {
        float v = fmaf(xa, wa[j], fmaf(xb, wb[j], bb[j]));
        o[j] = (_Float16)tanh_fast(v);
    }
    *(f16x8*)(H + (size_t)row * 1024 + j0) = o;
}

// ---------------------------------------------------------------------------
// GEMM + bias + tanh, f16, pipelined producer/consumer, 128x128 tile, BK=32.
// 320 threads: waves 0-3 consume (2x2 of 64x64, 4x4 16x16x32 frags);
// wave 4 produces into lds[3] ring:
//   prologue: load t0 -> write buf0 -> issue loads t1 -> lgkm -> s_barrier
//   iter t:   ds_write buf[(t+1)%3] (auto vmcnt waits loads issued 1 iter
//             ago), issue loads t+2 (stay in flight across the RAW barrier),
//             lgkm drain, s_barrier.
// Consumers read buf[t%3] — always 2 barriers away from the producer's
// write target. KB = diag block: cols [n0,n0+128) need k in [(n0/KB)*KB,+KB).
// FUSE: layer3+final — tanh(pre).Wl partial, 16-lane shfl reduce, one fp32
// atomicAdd per row (out pre-initialized to b_last).
// ---------------------------------------------------------------------------
template <bool FUSE>
__global__ __launch_bounds__(320)
void gemm_tanh_f16(const _Float16* __restrict__ A, const _Float16* __restrict__ Bt,
                   const float* __restrict__ bias, _Float16* __restrict__ C,
                   const float* __restrict__ Wl, float* __restrict__ out, int KB) {
    __shared__ _Float16 lds[3][8192];    // ring: [A:0..4095 | B:4096..8191] x3

    const int tid  = threadIdx.x;
    const int lane = tid & 63;
    const int wave = tid >> 6;           // 0..4
    const int m0 = blockIdx.x * 128;     // m fast (proven cache order)
    const int n0 = blockIdx.y * 128;
    const int kbeg   = (n0 / KB) * KB;
    const int kiters = KB >> 5;

    if (wave == 4) {
        // ---------------- producer (one iteration ahead) ----------------
        const int row0 = lane >> 2;               // 0..15
        const int sg   = (lane & 3) << 3;
        const _Float16* pA = A  + (size_t)(m0 + row0) * 1024 + kbeg + sg;
        const _Float16* pB = Bt + (size_t)(n0 + row0) * 1024 + kbeg + sg;
        const int ls = lane * 8;                  // elem offset; +512 per i
        f16x8 rA[8], rB[8];
        #pragma unroll
        for (int i = 0; i < 8; ++i) {             // tile 0
            rA[i] = *(const f16x8*)(pA + (size_t)i * 16384);
            rB[i] = *(const f16x8*)(pB + (size_t)i * 16384);
        }
        #pragma unroll
        for (int i = 0; i < 8; ++i) {
            *(f16x8*)(&lds[0][ls + i * 512]) = rA[i];
            *(f16x8*)(&lds[0][4096 + ls + i * 512]) = rB[i];
        }
        if (kiters > 1) {                         // tile 1: in flight
            #pragma unroll
            for (int i = 0; i < 8; ++i) {
                rA[i] = *(const f16x8*)(pA + (size_t)i * 16384 + 32);
                rB[i] = *(const f16x8*)(pB + (size_t)i * 16384 + 32);
            }
        }
        asm volatile("s_waitcnt lgkmcnt(0)" ::: "memory");
        asm volatile("s_barrier" ::: "memory");   // buf0 ready (prologue)
        int widx = 1;                             // write buffer index
        for (int t = 0; t < kiters; ++t) {
            if (t + 1 < kiters) {
                _Float16* dst = &lds[widx][0];
                widx = (widx == 2) ? 0 : widx + 1;
                #pragma unroll
                for (int i = 0; i < 8; ++i) {     // auto vmcnt waits t+1 loads
                    *(f16x8*)(dst + ls + i * 512) = rA[i];
                    *(f16x8*)(dst + 4096 + ls + i * 512) = rB[i];
                }
                if (t + 2 < kiters) {             // t+2: in flight over barrier
                    const size_t d = (size_t)(t + 2) << 5;
                    #pragma unroll
                    for (int i = 0; i < 8; ++i) {
                        rA[i] = *(const f16x8*)(pA + (size_t)i * 16384 + d);
                        rB[i] = *(const f16x8*)(pB + (size_t)i * 16384 + d);
                    }
                }
                asm volatile("s_waitcnt lgkmcnt(0)" ::: "memory");
            }
            asm volatile("s_barrier" ::: "memory");
        }
        return;                                   // epilogue is consumer-only
    }

    // ---------------- consumers (waves 0-3) ----------------
    const int wm = (wave & 1) << 6;
    const int wn = (wave >> 1) << 6;
    const int r = lane & 15;
    const int q = lane >> 4;

    floatx4 acc[4][4];
    #pragma unroll
    for (int i = 0; i < 4; ++i)
        #pragma unroll
        for (int j = 0; j < 4; ++j)
            acc[i][j] = floatx4{0.f, 0.f, 0.f, 0.f};

    __syncthreads();                     // pairs with producer prologue barrier
    int ridx = 0;                        // read buffer index
    for (int t = 0; t < kiters; ++t) {
        const _Float16* As = &lds[ridx][0];
        const _Float16* Bs = As + 4096;
        ridx = (ridx == 2) ? 0 : ridx + 1;
        f16x8 af[4], bf[4];
        #pragma unroll
        for (int i = 0; i < 4; ++i) {
            af[i] = *(const f16x8*)(As + (wm + i * 16 + r) * 32 + q * 8);
            bf[i] = *(const f16x8*)(Bs + (wn + i * 16 + r) * 32 + q * 8);
        }
        #pragma unroll
        for (int i = 0; i < 4; ++i)
            #pragma unroll
            for (int j = 0; j < 4; ++j)
                acc[i][j] = __builtin_amdgcn_mfma_f32_16x16x32_f16(af[i], bf[j], acc[i][j], 0, 0, 0);
        __syncthreads();
    }

    // Epilogue. C/D layout: col=lane&15, row=(lane>>4)*4+reg.
    float bv[4], wlv[4];
    #pragma unroll
    for (int j = 0; j < 4; ++j) {
        const int col = n0 + wn + j * 16 + r;
        bv[j] = bias[col];
        if (FUSE) wlv[j] = Wl[col];
    }
    #pragma unroll
    for (int i = 0; i < 4; ++i) {
        const int row0 = m0 + wm + i * 16 + q * 4;
        #pragma unroll
        for (int rr = 0; rr < 4; ++rr) {
            if (!FUSE) {
                #pragma unroll
                for (int j = 0; j < 4; ++j) {
                    float o = tanh_fast(acc[i][j][rr] + bv[j]);
                    const int col = n0 + wn + j * 16 + r;
                    C[(size_t)(row0 + rr) * 1024 + col] = (_Float16)o;
                }
            } else {
                float p = 0.f;
                #pragma unroll
                for (int j = 0; j < 4; ++j)
                    p = fmaf(tanh_fast(acc[i][j][rr] + bv[j]), wlv[j], p);
                p += __shfl_down(p, 8);  // reduce the 16 r-lanes
                p += __shfl_down(p, 4);
                p += __shfl_down(p, 2);
                p += __shfl_down(p, 1);
                if (r == 0) atomicAdd(out + row0 + rr, p);
            }
        }
    }
}

// ---------------------------------------------------------------------------
extern "C" void kernel_launch(void* const* d_in, const int* in_sizes, int n_in,
                              void* d_out, int out_size, void* d_ws, size_t ws_size,
                              hipStream_t stream) {
    const float* X  = (const float*)d_in[0];
    const float* W0 = (const float*)d_in[1];
    const float* b0 = (const float*)d_in[2];
    const float* W1 = (const float*)d_in[3];
    const float* b1 = (const float*)d_in[4];
    const float* W2 = (const float*)d_in[5];
    const float* b2 = (const float*)d_in[6];
    const float* W3 = (const float*)d_in[7];
    const float* b3 = (const float*)d_in[8];
    const float* Wl = (const float*)d_in[9];
    const float* bl = (const float*)d_in[10];
    float* out = (float*)d_out;

    const int Nrows = in_sizes[0] / 2;                 // 65536
    const size_t WT = 1024 * 1024;                     // elems per f16 weight plane
    const size_t wt_bytes = 3 * WT * 2;                // 6 MiB
    const size_t slack = 512;

    int R = 0;
    const int Rcap = Nrows < 32768 ? Nrows : 32768;
    for (int r = Rcap; r >= 256; r >>= 1)
        if ((size_t)2 * r * 2048 + wt_bytes + slack <= ws_size) { R = r; break; }
    if (!R) return;

    _Float16* wsp = (_Float16*)d_ws;
    _Float16* Wt1 = wsp;
    _Float16* Wt2 = Wt1 + WT;
    _Float16* Wt3 = Wt2 + WT;
    const size_t plane = (size_t)R * 1024;
    _Float16* P0 = Wt3 + WT;
    _Float16* P1 = P0 + plane;

    const dim3 tb(256);
    transposeH3<<<dim3(32, 32, 3), tb, 0, stream>>>(W1, W2, W3, Wt1, Wt2, Wt3);
    init_out<<<Nrows / 256, tb, 0, stream>>>(out, bl);

    const int nchunks = Nrows / R;
    for (int c = 0; c < nchunks; ++c) {
        const float* Xc = X + (size_t)c * R * 2;
        float* outc = out + (size_t)c * R;

        layer0_kernel<<<R / 2, tb, 0, stream>>>(Xc, W0, b0, P0);

        const dim3 tg(320);
        const dim3 gg(R / 128, 8);                    // m fast
        gemm_tanh_f16<false><<<gg, tg, 0, stream>>>(P0, Wt1, b1, P1, nullptr, nullptr, 1024);
        gemm_tanh_f16<false><<<gg, tg, 0, stream>>>(P1, Wt2, b2, P0, nullptr, nullptr, 512);
        gemm_tanh_f16<true ><<<gg, tg, 0, stream>>>(P0, Wt3, b3, nullptr, Wl, outc, 256);
    }
}